// Round 1
// baseline (168.800 us; speedup 1.0000x reference)
//
#include <hip/hip_runtime.h>
#include <math.h>

#define HH 64
#define WW 64
#define CIN 256
#define COUT 256
#define KKT 9
#define HWSZ 4096
#define VP 260                 // LDS row pitch in shorts

typedef __bf16  v8bf   __attribute__((ext_vector_type(8)));
typedef float   v4f    __attribute__((ext_vector_type(4)));
typedef short   short8 __attribute__((ext_vector_type(8)));
typedef unsigned short ushort4v __attribute__((ext_vector_type(4)));

__device__ inline unsigned short f2bf(float f) {   // RNE
    union { float f; unsigned u; } uf; uf.f = f;
    unsigned r = uf.u + 0x7fff + ((uf.u >> 16) & 1);
    return (unsigned short)(r >> 16);
}
__device__ inline float bf2f(unsigned short u) {
    union { unsigned u; float f; } uf; uf.u = ((unsigned)u) << 16;
    return uf.f;
}

// ---------------------------------------------------------------------------
// Merged prep kernel. Blocks 0..255: x -> x_t (channel-last bf16).
// Blocks 256..511: w -> wprep (LDS-staged, coalesced 16B writes).
// Blocks 512..583: w_off -> woffp.
// ---------------------------------------------------------------------------
__global__ __launch_bounds__(256) void k_prep(const float* __restrict__ x,
                                              const float* __restrict__ w,
                                              const float* __restrict__ w_off,
                                              unsigned short* __restrict__ x_t,
                                              unsigned short* __restrict__ wprep,
                                              unsigned short* __restrict__ woffp) {
    __shared__ float s_w[2304];
    int id  = blockIdx.x;
    int tid = threadIdx.x;
    if (id < 256) {
        int b  = id >> 6;
        int h  = id & 63;
        int px  = tid & 63;
        int oct = tid >> 6;
        const float* xr = x + (((size_t)b * CIN) * HH + h) * WW;
        unsigned short* orow = x_t + (((size_t)id) * WW + px) * CIN;
        for (int g = 0; g < 8; g++) {
            int cb = g * 32 + oct * 8;
            unsigned short v[8];
#pragma unroll
            for (int j = 0; j < 8; j++)
                v[j] = f2bf(xr[(size_t)(cb + j) * HWSZ + px]);
            *(short8*)(orow + cb) = *(short8*)v;
        }
    } else if (id < 512) {
        int o = id - 256;
        for (int i = tid; i < 2304; i += 256) s_w[i] = w[(size_t)o * 2304 + i];
        __syncthreads();
        for (int u = tid; u < 576; u += 256) {
            int t  = u >> 3;
            int kq = u & 7;
            unsigned short v[4];
#pragma unroll
            for (int j = 0; j < 4; j++) {
                int kp = t * 32 + kq * 4 + j;
                int kk = kp >> 8;
                int c  = kp & 255;
                v[j] = f2bf(s_w[c * 9 + kk]);
            }
            *(ushort4v*)&wprep[((size_t)(t * 256 + o)) * 32 + kq * 4] = *(ushort4v*)v;
        }
    } else {
        int t = id - 512;              // 0..71
#pragma unroll
        for (int i = 0; i < 4; i++) {
            int idx = i * 256 + tid;
            int och = idx >> 5;
            int ki  = idx & 31;
            int kp  = t * 32 + ki;
            int kk  = kp >> 8;
            int c   = kp & 255;
            float v = (och < 27) ? w_off[((size_t)och * 256 + c) * 9 + kk] : 0.f;
            woffp[(size_t)t * 1024 + idx] = f2bf(v);
        }
    }
}

// ---------------------------------------------------------------------------
// Fully fused kernel. Grid 512 = (b, h, px-half). 512 thr (8 waves).
// Prologue: stage 3x34x256 halo -> offset-conv MFMA (27och x 32px, 4-way
// K-split) -> LDS reduce to s_om -> Phase A (sampling params from s_om).
// Main loop: double-buffered s_v, gathers for kk+1 issued before a raw
// s_barrier (lgkmcnt-only drain) so they fly during kk's MFMA phase.
// LDS regions time-aliased: s_row(53KB) -> s_red(16.9KB) -> s_v dbuf(33.3KB).
// Total 65.8KB -> 2 blocks/CU (16 waves/CU).
// ---------------------------------------------------------------------------
__global__ __launch_bounds__(512, 4) void k_main(const unsigned short* __restrict__ x_t,
                                                 const unsigned short* __restrict__ wprep,
                                                 const unsigned short* __restrict__ woffp,
                                                 const float* __restrict__ b_off,
                                                 float* __restrict__ out) {
    int id    = blockIdx.x;
    int g     = id & 7;
    int phalf = (id >> 3) & 1;
    int hi    = (id >> 4) & 7;
    int b     = id >> 7;
    int h     = g * 8 + hi;
    int p0    = phalf * 32;
    int tid  = threadIdx.x;
    int lane = tid & 63;
    int oct  = tid >> 6;               // wave 0..7
    int m16  = lane & 15;
    int quad = lane >> 4;

    __shared__ __align__(16) unsigned short s_reg[3 * 34 * VP];   // 53 KB, aliased
    __shared__ int4   s_base[KKT][32];
    __shared__ float4 s_wt  [KKT][32];
    __shared__ float  s_om  [27][33];

    const unsigned short* xb = x_t + (size_t)b * HWSZ * CIN;

    // ---- Phase 0: stage 3 rows x 34 px x 256 ch ----
    for (int u = tid; u < 3 * 1088; u += 512) {     // short8 units
        int row = u / 1088;
        int rem = u - row * 1088;
        int px  = rem >> 5;
        int c8  = (rem & 31) * 8;
        int y   = h + row - 1;
        int xg  = p0 + px - 1;
        short8 val = (short8)0;
        if ((unsigned)y < HH && (unsigned)xg < WW)
            val = *(const short8*)(xb + ((size_t)y * WW + xg) * CIN + c8);
        *(short8*)&s_reg[(row * 34 + px) * VP + c8] = val;
    }
    __syncthreads();

    // ---- Phase 1: offset conv MFMA. 8 waves = 4 K-groups x 2 px-tiles ----
    {
        int g2  = oct >> 1;            // 0..3
        int ntw = oct & 1;
        v4f oa[2];
        oa[0] = (v4f)(0.f);
        oa[1] = (v4f)(0.f);
#pragma unroll
        for (int ky = 0; ky < 3; ky++)
#pragma unroll
        for (int kx = 0; kx < 3; kx++)
#pragma unroll
        for (int c2 = 0; c2 < 2; c2++) {
            int ch = c2 * 4 + g2;
            int t  = (ky * 3 + kx) * 8 + ch;
            const unsigned short* wp = woffp + (size_t)t * 1024;
            short8 af0 = *(const short8*)(wp + m16 * 32 + quad * 8);
            short8 af1 = *(const short8*)(wp + (16 + m16) * 32 + quad * 8);
            short8 bfr = *(const short8*)
                &s_reg[(ky * 34 + ntw * 16 + m16 + kx) * VP + ch * 32 + quad * 8];
            oa[0] = __builtin_amdgcn_mfma_f32_16x16x32_bf16(
                __builtin_bit_cast(v8bf, af0), __builtin_bit_cast(v8bf, bfr), oa[0], 0, 0, 0);
            oa[1] = __builtin_amdgcn_mfma_f32_16x16x32_bf16(
                __builtin_bit_cast(v8bf, af1), __builtin_bit_cast(v8bf, bfr), oa[1], 0, 0, 0);
        }
        __syncthreads();                           // s_row dead from here
        float* s_red = (float*)s_reg;              // [4][32][33]
#pragma unroll
        for (int mt = 0; mt < 2; mt++)
#pragma unroll
            for (int r = 0; r < 4; r++)
                s_red[(g2 * 32 + mt * 16 + quad * 4 + r) * 33 + ntw * 16 + m16] = oa[mt][r];
        __syncthreads();
        for (int i2 = tid; i2 < 27 * 32; i2 += 512) {
            int och = i2 >> 5;
            int px  = i2 & 31;
            float s = s_red[och * 33 + px]         + s_red[(32 + och) * 33 + px]
                    + s_red[(64 + och) * 33 + px]  + s_red[(96 + och) * 33 + px]
                    + b_off[och];
            s_om[och][px] = s;
        }
        __syncthreads();
    }

    // ---- Phase A: sampling params for 9 kk x 32 px (from LDS s_om) ----
    for (int i = tid; i < KKT * 32; i += 512) {
        int kk = i >> 5;
        int pl = i & 31;
        int p  = p0 + pl;
        float offy = s_om[2 * kk][pl];
        float offx = s_om[2 * kk + 1][pl];
        float mv   = s_om[18 + kk][pl];
        int ky = kk / 3, kx = kk - 3 * (kk / 3);
        float py = (float)(h - 1 + ky) + offy;
        float px = (float)(p - 1 + kx) + offx;
        float y0f = floorf(py);
        float x0f = floorf(px);
        float ly = py - y0f, lx = px - x0f;
        int y0 = (int)y0f, x0 = (int)x0f;
        float m = 1.f / (1.f + __expf(-mv));
        bool yv0 = (unsigned)y0       < HH;
        bool yv1 = (unsigned)(y0 + 1) < HH;
        bool xv0 = (unsigned)x0       < WW;
        bool xv1 = (unsigned)(x0 + 1) < WW;
        int y0c = min(max(y0, 0), HH - 1);
        int y1c = min(max(y0 + 1, 0), HH - 1);
        int x0c = min(max(x0, 0), WW - 1);
        int x1c = min(max(x0 + 1, 0), WW - 1);
        s_base[kk][pl] = make_int4((y0c * WW + x0c) * CIN, (y0c * WW + x1c) * CIN,
                                   (y1c * WW + x0c) * CIN, (y1c * WW + x1c) * CIN);
        s_wt[kk][pl] = make_float4(
            (yv0 && xv0) ? (1.f - ly) * (1.f - lx) * m : 0.f,
            (yv0 && xv1) ? (1.f - ly) * lx         * m : 0.f,
            (yv1 && xv0) ? ly * (1.f - lx)         * m : 0.f,
            (yv1 && xv1) ? ly * lx                 * m : 0.f);
    }
    __syncthreads();

    v4f acc[2][2];
#pragma unroll
    for (int mt = 0; mt < 2; mt++)
#pragma unroll
        for (int nt = 0; nt < 2; nt++) acc[mt][nt] = (v4f)(0.f);

    const unsigned short* xc = xb + lane * 4;

    // prologue prefetch for kk = 0
    ushort4v tt[4][4];
#pragma unroll
    for (int i = 0; i < 4; i++) {
        int4 bp = s_base[0][oct * 4 + i];
        tt[i][0] = *(const ushort4v*)(xc + bp.x);
        tt[i][1] = *(const ushort4v*)(xc + bp.y);
        tt[i][2] = *(const ushort4v*)(xc + bp.z);
        tt[i][3] = *(const ushort4v*)(xc + bp.w);
    }

#pragma unroll
    for (int kk = 0; kk < KKT; kk++) {
        unsigned short* sv = s_reg + (kk & 1) * (32 * VP);   // double buffer

        // ---- combine staged regs -> s_v[cur] ----
#pragma unroll
        for (int i = 0; i < 4; i++) {
            int pl = oct * 4 + i;
            float4 wt = s_wt[kk][pl];
            unsigned short vv[4];
#pragma unroll
            for (int j = 0; j < 4; j++) {
                float val = wt.x * bf2f(tt[i][0][j]) + wt.y * bf2f(tt[i][1][j])
                          + wt.z * bf2f(tt[i][2][j]) + wt.w * bf2f(tt[i][3][j]);
                vv[j] = f2bf(val);
            }
            *(ushort4v*)&sv[pl * VP + lane * 4] = *(ushort4v*)vv;
        }

        // ---- issue gathers for kk+1; they stay in flight across the barrier
        if (kk < KKT - 1) {
#pragma unroll
            for (int i = 0; i < 4; i++) {
                int4 bp = s_base[kk + 1][oct * 4 + i];
                tt[i][0] = *(const ushort4v*)(xc + bp.x);
                tt[i][1] = *(const ushort4v*)(xc + bp.y);
                tt[i][2] = *(const ushort4v*)(xc + bp.z);
                tt[i][3] = *(const ushort4v*)(xc + bp.w);
            }
        }

        // drain only LDS ops (ds_write of s_v); do NOT drain vmcnt —
        // __syncthreads() would and that kills the prefetch overlap.
        asm volatile("s_waitcnt lgkmcnt(0)" ::: "memory");
        __builtin_amdgcn_s_barrier();
        __builtin_amdgcn_sched_barrier(0);

        // ---- 8 K-chunks of MFMA for this kk ----
#pragma unroll 2
        for (int ch = 0; ch < 8; ch++) {
            int t = kk * 8 + ch;
            const unsigned short* wp = wprep + ((size_t)t * 256 + oct * 32) * 32;
            short8 af0 = *(const short8*)(wp + m16 * 32 + quad * 8);
            short8 af1 = *(const short8*)(wp + (16 + m16) * 32 + quad * 8);
            short8 bfr[2];
#pragma unroll
            for (int nt = 0; nt < 2; nt++)
                bfr[nt] = *(const short8*)&sv[(nt * 16 + m16) * VP + ch * 32 + quad * 8];
#pragma unroll
            for (int nt = 0; nt < 2; nt++) {
                acc[0][nt] = __builtin_amdgcn_mfma_f32_16x16x32_bf16(
                    __builtin_bit_cast(v8bf, af0), __builtin_bit_cast(v8bf, bfr[nt]),
                    acc[0][nt], 0, 0, 0);
                acc[1][nt] = __builtin_amdgcn_mfma_f32_16x16x32_bf16(
                    __builtin_bit_cast(v8bf, af1), __builtin_bit_cast(v8bf, bfr[nt]),
                    acc[1][nt], 0, 0, 0);
            }
        }
        // no trailing barrier: next iter writes the OTHER buffer; the hazard
        // write(buf,kk+2) vs read(buf,kk) is fenced by barrier(kk+1).
    }

    // ---- epilogue ----
    float* ob = out + ((size_t)b * COUT) * HWSZ + h * WW + p0;
#pragma unroll
    for (int mt = 0; mt < 2; mt++)
#pragma unroll
        for (int nt = 0; nt < 2; nt++)
#pragma unroll
            for (int r = 0; r < 4; r++) {
                int o = oct * 32 + mt * 16 + quad * 4 + r;
                ob[(size_t)o * HWSZ + nt * 16 + m16] = acc[mt][nt][r];
            }
}

extern "C" void kernel_launch(void* const* d_in, const int* in_sizes, int n_in,
                              void* d_out, int out_size, void* d_ws, size_t ws_size,
                              hipStream_t stream) {
    const float* x     = (const float*)d_in[0];
    const float* w_off = (const float*)d_in[1];
    const float* b_off = (const float*)d_in[2];
    const float* w     = (const float*)d_in[3];
    float* out = (float*)d_out;

    unsigned short* x_t   = (unsigned short*)d_ws;           // 4*4096*256 bf16
    unsigned short* wprep = x_t + (size_t)4 * HWSZ * CIN;    // 589824 bf16
    unsigned short* woffp = wprep + 589824;                  // 73728 bf16

    hipLaunchKernelGGL(k_prep, dim3(584), dim3(256), 0, stream, x, w, w_off, x_t, wprep, woffp);
    hipLaunchKernelGGL(k_main, dim3(512), dim3(512), 0, stream, x_t, wprep, woffp, b_off, out);
}